// Round 17
// baseline (68.000 us; speedup 1.0000x reference)
//
#include <hip/hip_runtime.h>

namespace {
constexpr int NB  = 131072;
constexpr int NJ  = 24;
constexpr int PAR[NJ] = {0,0,0,0,1,2,3,4,5,6,7,8,9,9,9,12,13,14,16,17,18,19,20,21};
constexpr int BLK = 64;         // one wave per block; batches per block
constexpr int SOT = 68;         // LDS row stride (floats) oT staging (64 data + 4 pad)
constexpr int SPO = 76;         // LDS row stride (floats) oP staging (72 data + 4 pad)
constexpr int LDSF = BLK * SPO; // 19456 B -> 8 blocks/CU
}

typedef float f32x4 __attribute__((ext_vector_type(4)));

// Champion (r8: single-wave blocks, zero barriers, direct per-lane loads,
// LDS output transposes, nt stores) + GROUP-SCOPED load batching: both quads'
// rot loads (18 f4) issue before either quad's compute, halving the number of
// exposed L3 round-trips per group. Unlike r11's failed cross-loop double
// buffer, the extra live state (+36 floats) is scoped to one group body.
__global__ __launch_bounds__(BLK) void pose_kernel(
    const float* __restrict__ rot,
    const float* __restrict__ pos,
    float* __restrict__ outT,
    float* __restrict__ outP)
{
    __shared__ __align__(16) float lds[LDSF];
    const int t  = threadIdx.x;   // 0..63, lane == batch within block
    const int b0 = blockIdx.x * BLK;

    const float* prow = pos + (size_t)(b0 + t) * 72;   // this thread's pos row
    const float* rrow = rot + (size_t)(b0 + t) * 216;  // this thread's rot row

    float Rg[NJ][9];
    float tg[NJ][3];
    float carry1[9];   // P of joints 5,6,7   (needed by group 1)
    float carry2[6];   // P of joints 13,14   (needed by group 2)

    #pragma unroll
    for (int g = 0; g < 3; ++g) {
        // ---- group-local positions: joints 8g..8g+7 = floats [24g, 24g+24) ----
        float Pg[24];
        #pragma unroll
        for (int i = 0; i < 6; ++i) {
            f32x4 v = *reinterpret_cast<const f32x4*>(prow + 24 * g + 4 * i);
            Pg[4*i+0] = v.x; Pg[4*i+1] = v.y; Pg[4*i+2] = v.z; Pg[4*i+3] = v.w;
        }

        // ---- issue BOTH quads' rot loads up front (18 f4, one latency wave) ----
        float bufA[36], bufB[36];
        #pragma unroll
        for (int i = 0; i < 9; ++i) {
            f32x4 v = *reinterpret_cast<const f32x4*>(rrow + 72 * g + 4 * i);
            bufA[4*i+0] = v.x; bufA[4*i+1] = v.y; bufA[4*i+2] = v.z; bufA[4*i+3] = v.w;
        }
        #pragma unroll
        for (int i = 0; i < 9; ++i) {
            f32x4 v = *reinterpret_cast<const f32x4*>(rrow + 72 * g + 36 + 4 * i);
            bufB[4*i+0] = v.x; bufB[4*i+1] = v.y; bufB[4*i+2] = v.z; bufB[4*i+3] = v.w;
        }

        #pragma unroll
        for (int q = 0; q < 2; ++q) {           // quad = 4 joints
            const float* buf = (q == 0) ? bufA : bufB;   // static after unroll

            // ---- compute 4 joints (parent always < j; all indices static) ----
            #pragma unroll
            for (int l = 0; l < 4; ++l) {
                const int j  = 8 * g + 4 * q + l;
                const int pj = PAR[j];
                const float* L = buf + 9 * l;

                if (j == 0) {
                    #pragma unroll
                    for (int k = 0; k < 9; ++k) Rg[0][k] = L[k];
                    tg[0][0] = Pg[0]; tg[0][1] = Pg[1]; tg[0][2] = Pg[2];
                } else {
                    float pxp, pyp, pzp;
                    if (pj >= 8 * g) {                 // parent in this group
                        const int lp = 3 * pj - 24 * g;
                        pxp = Pg[lp]; pyp = Pg[lp+1]; pzp = Pg[lp+2];
                    } else if (g == 1) {               // parent in {5,6,7}
                        const int ci = 3 * (pj - 5);
                        pxp = carry1[ci]; pyp = carry1[ci+1]; pzp = carry1[ci+2];
                    } else {                           // g==2, parent in {13,14}
                        const int ci = 3 * (pj - 13);
                        pxp = carry2[ci]; pyp = carry2[ci+1]; pzp = carry2[ci+2];
                    }
                    const int lj = 3 * j - 24 * g;
                    float rel[3] = { Pg[lj] - pxp, Pg[lj+1] - pyp, Pg[lj+2] - pzp };
                    #pragma unroll
                    for (int r = 0; r < 3; ++r) {
                        #pragma unroll
                        for (int c = 0; c < 3; ++c) {
                            Rg[j][3*r+c] = Rg[pj][3*r+0] * L[0+c]
                                         + Rg[pj][3*r+1] * L[3+c]
                                         + Rg[pj][3*r+2] * L[6+c];
                        }
                        tg[j][r] = Rg[pj][3*r+0] * rel[0]
                                 + Rg[pj][3*r+1] * rel[1]
                                 + Rg[pj][3*r+2] * rel[2]
                                 + tg[pj][r];
                    }
                }
            }

            // ---- oT: stage this quad (64 floats/row) then coalesced nt write ----
            #pragma unroll
            for (int l = 0; l < 4; ++l) {
                const int j  = 8 * g + 4 * q + l;
                const int lj = 3 * j - 24 * g;
                float px = Pg[lj], py = Pg[lj+1], pz = Pg[lj+2];
                #pragma unroll
                for (int r = 0; r < 3; ++r) {
                    float ib = Rg[j][3*r]*px + Rg[j][3*r+1]*py + Rg[j][3*r+2]*pz;
                    *reinterpret_cast<f32x4*>(&lds[t * SOT + (l*4 + r) * 4]) =
                        f32x4{Rg[j][3*r], Rg[j][3*r+1], Rg[j][3*r+2], tg[j][r] - ib};
                }
                *reinterpret_cast<f32x4*>(&lds[t * SOT + (l*4 + 3) * 4]) =
                    f32x4{0.f, 0.f, 0.f, 1.f};
            }
            {
                float* gp = outT + (size_t)b0 * 384 + (8 * g + 4 * q) * 16;
                #pragma unroll
                for (int i = 0; i < 16; ++i) {
                    int f = t + BLK * i;          // 1024 f4 = 64 rows x 16
                    int row = f >> 4, col = f & 15;
                    f32x4 v = *reinterpret_cast<const f32x4*>(&lds[row * SOT + col * 4]);
                    __builtin_nontemporal_store(
                        v, reinterpret_cast<f32x4*>(gp + (size_t)row * 384 + col * 4));
                }
            }
        }

        // ---- save cross-group parent positions (all static) ----
        if (g == 0) {
            #pragma unroll
            for (int k = 0; k < 9; ++k) carry1[k] = Pg[15 + k];   // joints 5,6,7
        } else if (g == 1) {
            #pragma unroll
            for (int k = 0; k < 6; ++k) carry2[k] = Pg[15 + k];   // joints 13,14
        }
    }

    // ---- oP: stage all 24 translations (72 floats/row), coalesced nt write ----
    #pragma unroll
    for (int i = 0; i < 18; ++i) {
        float vals[4];
        #pragma unroll
        for (int k = 0; k < 4; ++k) {
            int e = 4*i + k;                  // 0..71, static
            vals[k] = tg[e / 3][e % 3];
        }
        *reinterpret_cast<f32x4*>(&lds[t * SPO + i * 4]) =
            f32x4{vals[0], vals[1], vals[2], vals[3]};
    }
    {
        float* gp = outP + (size_t)b0 * 72;
        #pragma unroll
        for (int i = 0; i < 18; ++i) {
            int f = t + BLK * i;              // 1152 f4 = 64 rows x 18
            int row = f / 18, col = f % 18;
            f32x4 v = *reinterpret_cast<const f32x4*>(&lds[row * SPO + col * 4]);
            __builtin_nontemporal_store(
                v, reinterpret_cast<f32x4*>(gp + (size_t)row * 72 + col * 4));
        }
    }
}

extern "C" void kernel_launch(void* const* d_in, const int* in_sizes, int n_in,
                              void* d_out, int out_size, void* d_ws, size_t ws_size,
                              hipStream_t stream) {
    const float* rot = (const float*)d_in[0];
    const float* pos = (const float*)d_in[1];
    float* outT = (float*)d_out;
    float* outP = outT + (size_t)NB * NJ * 16;
    dim3 grid(NB / BLK), block(BLK);
    hipLaunchKernelGGL(pose_kernel, grid, block, 0, stream, rot, pos, outT, outP);
}